// Round 21
// baseline (440.973 us; speedup 1.0000x reference)
//
#include <hip/hip_runtime.h>

typedef unsigned int   u32;
typedef unsigned short u16;
typedef float f32x4  __attribute__((ext_vector_type(4)));
typedef float f32x16 __attribute__((ext_vector_type(16)));
typedef short s16x8  __attribute__((ext_vector_type(8)));
typedef u16   u16x4  __attribute__((ext_vector_type(4)));
typedef u16   u16x8  __attribute__((ext_vector_type(8)));
typedef u32   u32x4  __attribute__((ext_vector_type(4)));

#define DEVI __device__ __forceinline__

DEVI u16 f2bf(float f) {
  u32 u = __builtin_bit_cast(u32, f);
  u = (u + 0x7fffu + ((u >> 16) & 1u)) >> 16;
  return (u16)u;
}
DEVI float bf2f(u16 h) { u32 u = (u32)h << 16; return __builtin_bit_cast(float, u); }

DEVI void gload_lds16(const void* g, void* l) {
  __builtin_amdgcn_global_load_lds(
      (const __attribute__((address_space(1))) void*)g,
      (__attribute__((address_space(3))) void*)l, 16, 0, 0);
}

// ---------------------------------------------------------------------------
// fp32 -> bf16 pre-conversion of x and the four W matrices.
// ---------------------------------------------------------------------------
__global__ __launch_bounds__(256)
void convert_kernel(const float* __restrict__ x, const float* __restrict__ Wq,
                    const float* __restrict__ Wk, const float* __restrict__ Wv,
                    const float* __restrict__ Wo, u16* __restrict__ xb, u16* __restrict__ Wb)
{
  const int NX = 1 << 21;               // x vec8 chunks
  const int NT = NX + (1 << 21);        // + 4 * 2^19 W chunks
  for (int idx = blockIdx.x * 256 + threadIdx.x; idx < NT; idx += gridDim.x * 256) {
    const float* src; u16* dst; size_t off;
    if (idx < NX) { src = x; dst = xb; off = (size_t)idx * 8; }
    else {
      int i2 = idx - NX;
      int wsel = i2 >> 19, r = i2 & ((1 << 19) - 1);
      src = (wsel == 0) ? Wq : (wsel == 1) ? Wk : (wsel == 2) ? Wv : Wo;
      dst = Wb + (size_t)wsel * 4194304;
      off = (size_t)r * 8;
    }
    float4 a = *(const float4*)(src + off), b = *(const float4*)(src + off + 4);
    u16x8 o;
    o[0] = f2bf(a.x); o[1] = f2bf(a.y); o[2] = f2bf(a.z); o[3] = f2bf(a.w);
    o[4] = f2bf(b.x); o[5] = f2bf(b.y); o[6] = f2bf(b.z); o[7] = f2bf(b.w);
    *(u16x8*)(dst + off) = o;
  }
}

// ---------------------------------------------------------------------------
// 256x256 tile GEMM, counted-vmcnt double-buffered, split-kk (R19) +
// super-tile block ordering (R20) with 2x3 super-tile XCD chunks for the
// QKV shape (R21a). EPI 0 / wsel==1 fuses K-RoPE on the f32 accumulator
// via fast __sinf/__cosf + shfl_xor(1) pair exchange (R21b).
// ---------------------------------------------------------------------------
template<int EPI, int NBX>
__global__ __launch_bounds__(512, 2)
void gemm256(const u16* __restrict__ Ab, const u16* __restrict__ Bb,
             u16* __restrict__ Qh, u16* __restrict__ Kh, u16* __restrict__ Vt,
             float* __restrict__ Of, const int* __restrict__ pos)
{
  constexpr int K  = 2048;
  constexpr int NTILE = K / 64;          // 32
  __shared__ __attribute__((aligned(16))) char smem[131072];

  const int t = threadIdx.x;
  const int lane = t & 63, w = t >> 6;
  const int lo = lane & 15, hi = lane >> 4;
  const int wr = w >> 2, wc = w & 3;

  const int nwg = gridDim.x;
  const int cpx = nwg >> 3;
  const int sbid = (blockIdx.x & 7) * cpx + (blockIdx.x >> 3);
  const int g = sbid >> 4, l = sbid & 15;           // 4x4 super-tile
  int gx, gy;
  if (NBX == 24) {                    // 2x3 super-tile chunks per XCD (R21a)
    int c3 = g % 3, c2 = (g / 3) & 1, cm = g / 6;
    gx = (cm & 1) * 3 + c3;
    gy = (cm >> 1) * 2 + c2;
  } else {
    gx = g % (NBX / 4);
    gy = g / (NBX / 4);
  }
  const int bx = gx * 4 + (l & 3);
  const int by = gy * 4 + (l >> 2);
  const int m0 = by * 256, n0 = bx * 256;

  auto stage = [&](const u16* gbase, char* lds) {
#pragma unroll
    for (int j = 0; j < 4; ++j) {
      int chunk = j * 512 + w * 64 + lane;
      int row = chunk >> 3, cc = chunk & 7;
      const u16* g2 = gbase + (size_t)row * K + ((cc ^ (row & 7)) * 8);
      gload_lds16(g2, lds + (size_t)(j * 512 + w * 64) * 16);
    }
  };

  f32x4 zero = {0.f, 0.f, 0.f, 0.f};
  f32x4 acc[8][4];
#pragma unroll
  for (int i = 0; i < 8; ++i)
#pragma unroll
    for (int j = 0; j < 4; ++j) acc[i][j] = zero;

  const u16* Abase = Ab + (size_t)m0 * K;
  const u16* Bbase = Bb + (size_t)n0 * K;

  stage(Abase + 0 * 64, smem);
  stage(Bbase + 0 * 64, smem + 32768);
  stage(Abase + 1 * 64, smem + 65536);
  stage(Bbase + 1 * 64, smem + 65536 + 32768);

  for (int tt = 0; tt < NTILE; ++tt) {
    if (tt < NTILE - 1) {
      asm volatile("s_waitcnt vmcnt(8)\n\ts_barrier" ::: "memory");
    } else {
      asm volatile("s_waitcnt vmcnt(0)\n\ts_barrier" ::: "memory");
    }
    const char* Alp = smem + (size_t)(tt & 1) * 65536;
    const char* Blp = Alp + 32768;

    // ---- kk = 0: reads then pure-register MFMA cluster ----
    s16x8 af0[8], bf0[4];
#pragma unroll
    for (int i = 0; i < 8; ++i) {
      int ra = wr * 128 + i * 16 + lo;
      af0[i] = *(const s16x8*)(Alp + ra * 128 + ((hi * 16) ^ ((ra & 7) << 4)));
    }
#pragma unroll
    for (int j = 0; j < 4; ++j) {
      int rb = wc * 64 + j * 16 + lo;
      bf0[j] = *(const s16x8*)(Blp + rb * 128 + ((hi * 16) ^ ((rb & 7) << 4)));
    }
    __builtin_amdgcn_s_setprio(1);
#pragma unroll
    for (int i = 0; i < 8; ++i)
#pragma unroll
      for (int j = 0; j < 4; ++j)
        acc[i][j] = __builtin_amdgcn_mfma_f32_16x16x32_bf16(af0[i], bf0[j], acc[i][j], 0, 0, 0);
    __builtin_amdgcn_s_setprio(0);

    // ---- kk = 1 reads (overlap kk0 MFMA tail) ----
    s16x8 af1[8], bf1[4];
#pragma unroll
    for (int i = 0; i < 8; ++i) {
      int ra = wr * 128 + i * 16 + lo;
      af1[i] = *(const s16x8*)(Alp + ra * 128 + (((4 + hi) * 16) ^ ((ra & 7) << 4)));
    }
#pragma unroll
    for (int j = 0; j < 4; ++j) {
      int rb = wc * 64 + j * 16 + lo;
      bf1[j] = *(const s16x8*)(Blp + rb * 128 + (((4 + hi) * 16) ^ ((rb & 7) << 4)));
    }
    // all waves done reading buf[tt&1]; buffer dead -> stage before kk1 MFMA
    asm volatile("s_waitcnt lgkmcnt(0)\n\ts_barrier" ::: "memory");
    if (tt + 2 < NTILE) {
      char* dst = smem + (size_t)(tt & 1) * 65536;
      stage(Abase + (tt + 2) * 64, dst);
      stage(Bbase + (tt + 2) * 64, dst + 32768);
    }
    __builtin_amdgcn_s_setprio(1);
#pragma unroll
    for (int i = 0; i < 8; ++i)
#pragma unroll
      for (int j = 0; j < 4; ++j)
        acc[i][j] = __builtin_amdgcn_mfma_f32_16x16x32_bf16(af1[i], bf1[j], acc[i][j], 0, 0, 0);
    __builtin_amdgcn_s_setprio(0);
  }

  const int mb = m0 + wr * 128;
  const int nb = n0 + wc * 64;
  if (EPI == 0) {
    const int wsel = n0 >> 11;
    u16* Out = (wsel == 0) ? Qh : (wsel == 1) ? Kh : Vt;
    const float CF = -0.20762050593046014f;  // -log2(10000)/64
#pragma unroll
    for (int i = 0; i < 8; ++i) {
      int m = mb + i * 16 + hi * 4;
      int b = m >> 11, s0 = m & 2047;
#pragma unroll
      for (int j = 0; j < 4; ++j) {
        int nn = (nb + j * 16 + lo) & 2047;
        int h = nn >> 7, d = nn & 127;
        if (wsel == 0) {
#pragma unroll
          for (int r = 0; r < 4; ++r)
            Out[((size_t)((b * 16 + h) * 2048) + s0 + r) * 128 + d] = f2bf(acc[i][j][r]);
        } else if (wsel == 1) {
          // fused K-RoPE on f32 acc; fast sin/cos (no scratch path)
          float fr = exp2f(CF * (float)(d >> 1));
#pragma unroll
          for (int r = 0; r < 4; ++r) {
            float own = acc[i][j][r];
            float oth = __shfl_xor(own, 1, 64);
            float p = (float)pos[(b << 11) + s0 + r];
            float ang = p * fr;
            float cs = __cosf(ang), sn = __sinf(ang);
            float v = (lo & 1) ? (oth * sn + own * cs) : (own * cs - oth * sn);
            Out[((size_t)((b * 16 + h) * 2048) + s0 + r) * 128 + d] = f2bf(v);
          }
        } else {
          u16x4 v;
#pragma unroll
          for (int r = 0; r < 4; ++r) v[r] = f2bf(acc[i][j][r]);
          *(u16x4*)(Out + ((size_t)(b * 16 + h) * 128 + d) * 2048 + s0) = v;
        }
      }
    }
  } else {
#pragma unroll
    for (int i = 0; i < 8; ++i)
#pragma unroll
      for (int j = 0; j < 4; ++j) {
        int n = nb + j * 16 + lo;
#pragma unroll
        for (int r = 0; r < 4; ++r)
          Of[(size_t)(mb + i * 16 + hi * 4 + r) * 2048 + n] = acc[i][j][r];
      }
  }
}

// ---------------------------------------------------------------------------
// Legacy 128^2 GEMM (fallback path only)
// ---------------------------------------------------------------------------
template<int AM, int WM, int EPI>
__global__ __launch_bounds__(256, 2)
void gemm_nt(const void* __restrict__ Ap, const void* __restrict__ Wp, void* __restrict__ Cp)
{
  constexpr int K = 2048;
  __shared__ __attribute__((aligned(16))) u16 Al[128 * 64];
  __shared__ __attribute__((aligned(16))) u16 Bl[128 * 64];

  const int t = threadIdx.x;
  const int lane = t & 63, w = t >> 6;
  const int lo = lane & 15, hi = lane >> 4;
  const int wm = w >> 1, wn = w & 1;
  const int m0 = blockIdx.y * 128, n0 = blockIdx.x * 128;

  f32x4 zero = {0.f, 0.f, 0.f, 0.f};
  f32x4 acc[4][4];
#pragma unroll
  for (int i = 0; i < 4; ++i)
#pragma unroll
    for (int j = 0; j < 4; ++j) acc[i][j] = zero;

  for (int k0 = 0; k0 < K; k0 += 64) {
    __syncthreads();
    if (AM == 1) {
      const u16* A = (const u16*)Ap;
#pragma unroll
      for (int j = 0; j < 4; ++j) {
        int row = (w * 4 + j) * 8 + (lane >> 3);
        const u16* g = A + (size_t)(m0 + row) * K + k0 + (lane & 7) * 8;
        gload_lds16(g, (char*)Al + (w * 4 + j) * 1024);
      }
    } else {
      const float* A = (const float*)Ap;
#pragma unroll
      for (int c = 0; c < 2; ++c) {
        int chunk = c * 256 + t;
        int row = chunk >> 2, q = chunk & 3;
        const float4* g = reinterpret_cast<const float4*>(A + (size_t)(m0 + row) * K + k0 + q * 16);
        float4 v0 = g[0], v1 = g[1], v2 = g[2], v3 = g[3];
        u16x8 o0, o1;
        o0[0] = f2bf(v0.x); o0[1] = f2bf(v0.y); o0[2] = f2bf(v0.z); o0[3] = f2bf(v0.w);
        o0[4] = f2bf(v1.x); o0[5] = f2bf(v1.y); o0[6] = f2bf(v1.z); o0[7] = f2bf(v1.w);
        o1[0] = f2bf(v2.x); o1[1] = f2bf(v2.y); o1[2] = f2bf(v2.z); o1[3] = f2bf(v2.w);
        o1[4] = f2bf(v3.x); o1[5] = f2bf(v3.y); o1[6] = f2bf(v3.z); o1[7] = f2bf(v3.w);
        int swz = (row & 7) << 4;
        char* base = (char*)Al + row * 128;
        *(u16x8*)(base + ((q * 32)      ^ swz)) = o0;
        *(u16x8*)(base + ((q * 32 + 16) ^ swz)) = o1;
      }
    }
    if (WM == 1) {
      const u16* B = (const u16*)Wp;
#pragma unroll
      for (int j = 0; j < 4; ++j) {
        int row = (w * 4 + j) * 8 + (lane >> 3);
        const u16* g = B + (size_t)(n0 + row) * K + k0 + (lane & 7) * 8;
        gload_lds16(g, (char*)Bl + (w * 4 + j) * 1024);
      }
    } else {
      const float* B = (const float*)Wp;
#pragma unroll
      for (int c = 0; c < 2; ++c) {
        int chunk = c * 256 + t;
        int row = chunk >> 2, q = chunk & 3;
        const float4* g = reinterpret_cast<const float4*>(B + (size_t)(n0 + row) * K + k0 + q * 16);
        float4 v0 = g[0], v1 = g[1], v2 = g[2], v3 = g[3];
        u16x8 o0, o1;
        o0[0] = f2bf(v0.x); o0[1] = f2bf(v0.y); o0[2] = f2bf(v0.z); o0[3] = f2bf(v0.w);
        o0[4] = f2bf(v1.x); o0[5] = f2bf(v1.y); o0[6] = f2bf(v1.z); o0[7] = f2bf(v1.w);
        o1[0] = f2bf(v2.x); o1[1] = f2bf(v2.y); o1[2] = f2bf(v2.z); o1[3] = f2bf(v2.w);
        o1[4] = f2bf(v3.x); o1[5] = f2bf(v3.y); o1[6] = f2bf(v3.z); o1[7] = f2bf(v3.w);
        int swz = (row & 7) << 4;
        char* base = (char*)Bl + row * 128;
        *(u16x8*)(base + ((q * 32)      ^ swz)) = o0;
        *(u16x8*)(base + ((q * 32 + 16) ^ swz)) = o1;
      }
    }
    __syncthreads();
#pragma unroll
    for (int kk = 0; kk < 2; ++kk) {
      s16x8 af[4], bfr[4];
#pragma unroll
      for (int i = 0; i < 4; ++i) {
        int ra = wm * 64 + i * 16 + lo;
        int ca = (kk * 4 + hi) * 16; if (AM != 1) ca ^= (ra & 7) << 4;
        af[i]  = *(const s16x8*)((const char*)Al + ra * 128 + ca);
        int rb = wn * 64 + i * 16 + lo;
        int cb = (kk * 4 + hi) * 16; if (WM != 1) cb ^= (rb & 7) << 4;
        bfr[i] = *(const s16x8*)((const char*)Bl + rb * 128 + cb);
      }
#pragma unroll
      for (int i = 0; i < 4; ++i)
#pragma unroll
        for (int j = 0; j < 4; ++j)
          acc[i][j] = __builtin_amdgcn_mfma_f32_16x16x32_bf16(af[i], bfr[j], acc[i][j], 0, 0, 0);
    }
  }

  const int mb = m0 + wm * 64, nb = n0 + wn * 64;
  if (EPI == 0) {
    u16* Out = (u16*)Cp;
#pragma unroll
    for (int i = 0; i < 4; ++i)
#pragma unroll
      for (int j = 0; j < 4; ++j) {
        int n = nb + j * 16 + lo;
        int h = n >> 7, d = n & 127;
#pragma unroll
        for (int r = 0; r < 4; ++r) {
          int m = mb + i * 16 + hi * 4 + r;
          int b = m >> 11, s = m & 2047;
          Out[((size_t)((b * 16 + h) * 2048 + s)) * 128 + d] = f2bf(acc[i][j][r]);
        }
      }
  } else if (EPI == 1) {
    u16* Out = (u16*)Cp;
#pragma unroll
    for (int i = 0; i < 4; ++i)
#pragma unroll
      for (int j = 0; j < 4; ++j) {
        int n = nb + j * 16 + lo;
        int h = n >> 7, d = n & 127;
        int m = mb + i * 16 + hi * 4;
        int b = m >> 11, s = m & 2047;
        u16x4 v;
#pragma unroll
        for (int r = 0; r < 4; ++r) v[r] = f2bf(acc[i][j][r]);
        *(u16x4*)(Out + ((size_t)((b * 16 + h) * 128 + d)) * 2048 + s) = v;
      }
  } else {
    float* Out = (float*)Cp;
#pragma unroll
    for (int i = 0; i < 4; ++i)
#pragma unroll
      for (int j = 0; j < 4; ++j) {
        int n = nb + j * 16 + lo;
#pragma unroll
        for (int r = 0; r < 4; ++r) {
          int m = mb + i * 16 + hi * 4 + r;
          Out[(size_t)m * 2048 + n] = acc[i][j][r];
        }
      }
  }
}

// ---------------------------------------------------------------------------
// RoPE in-place on K only (fallback path only; fast path fuses into gemm)
// ---------------------------------------------------------------------------
__global__ __launch_bounds__(256)
void rope_k_kernel(u16* __restrict__ Kh, const int* __restrict__ pos)
{
  const int NP = 4 * 16 * 2048 * 64; // pairs
  const float C = -0.20762050593046014f; // -log2(10000)/64
  for (int idx = blockIdx.x * 256 + threadIdx.x; idx < NP; idx += gridDim.x * 256) {
    int i = idx & 63;
    int srow = idx >> 6;          // bh*2048 + s
    int s = srow & 2047;
    int b = srow >> 15;
    int p = pos[(b << 11) + s];
    float ang = (float)p * exp2f(C * (float)i);
    float sn, cs;
    sincosf(ang, &sn, &cs);
    u32* kp = (u32*)Kh + (size_t)srow * 64 + i;
    u32 v = *kp;
    float x1 = bf2f((u16)(v & 0xffffu)), x2 = bf2f((u16)(v >> 16));
    *kp = (u32)f2bf(x1 * cs - x2 * sn) | ((u32)f2bf(x1 * sn + x2 * cs) << 16);
  }
}

// ---------------------------------------------------------------------------
// Causal flash attention (R18 form, unchanged): swapped-operand 32x32 +
// cooperative double-buffered K/V LDS staging + 16-deep XOR swizzles.
// ---------------------------------------------------------------------------
__global__ __launch_bounds__(256, 2)
void attn_kernel(const u16* __restrict__ Qh, const u16* __restrict__ Kh,
                 const u16* __restrict__ Vt, const int* __restrict__ pos,
                 u16* __restrict__ AO)
{
  __shared__ __attribute__((aligned(16))) char smem[65536];

  const int t = threadIdx.x, lane = t & 63, w = t >> 6;
  const int q5 = lane & 31, h5 = lane >> 5;
  const int bid = blockIdx.x;
  const int bh = (((bid >> 3) & 7) << 3) | (bid & 7);   // XCD-slot pinned
  const int qt = bid >> 6;                  // 0..15
  const int qbase = (15 - qt) * 128;        // heavy tiles dispatch first
  const int b = bh >> 4;
  const int qrow0 = qbase + w * 32;
  const int q_abs = qrow0 + q5;

  const u16* Kb = Kh + (size_t)bh * 2048 * 128;   // [2048][128]
  const u16* Vb = Vt + (size_t)bh * 128 * 2048;   // [128][2048]

  auto stageKV = [&](int kv0, char* dst) {
#pragma unroll
    for (int j = 0; j < 4; ++j) {           // K: 1024 16B-chunks, 16-deep swz
      int chunk = j * 256 + w * 64 + lane;
      int row = chunk >> 4, cc = chunk & 15;
      const u16* g = Kb + (size_t)(kv0 + row) * 128 + ((cc ^ (row & 15)) * 8);
      gload_lds16(g, dst + (size_t)chunk * 16);
    }
#pragma unroll
    for (int j = 0; j < 4; ++j) {           // V: folded 64x256B, 16-deep swz
      int chunk = j * 256 + w * 64 + lane;
      int pr = chunk >> 4, o16 = chunk & 15;
      int orig = o16 ^ (pr & 15);
      int grow = ((orig >> 3) << 6) + pr;   // logical row = half*64 + pr
      const u16* g = Vb + (size_t)grow * 2048 + kv0 + ((orig & 7) * 8);
      gload_lds16(g, dst + 16384 + (size_t)chunk * 16);
    }
  };

  // ---- Q fragments with fused RoPE; softmax scale folded (registers) ----
  s16x8 qb[8];
  const float CF = -0.20762050593046014f;   // -log2(10000)/64
  const float QSCALE = 0.08838834764831845f * 1.4426950408889634f;
  {
    float p = (float)pos[(b << 11) + q_abs];
    const u16* qrow = Qh + ((size_t)bh * 2048 + q_abs) * 128;
#pragma unroll
    for (int kb = 0; kb < 8; ++kb) {
      s16x8 raw = *reinterpret_cast<const s16x8*>(qrow + kb * 16 + h5 * 8);
      s16x8 out;
#pragma unroll
      for (int u = 0; u < 4; ++u) {
        float x1 = bf2f((u16)raw[2 * u]), x2 = bf2f((u16)raw[2 * u + 1]);
        float ang = p * exp2f(CF * (float)(kb * 8 + h5 * 4 + u));
        float sn, cs; sincosf(ang, &sn, &cs);
        sn *= QSCALE; cs *= QSCALE;
        out[2 * u]     = (short)f2bf(x1 * cs - x2 * sn);
        out[2 * u + 1] = (short)f2bf(x1 * sn + x2 * cs);
      }
      qb[kb] = out;
    }
  }

  f32x16 o[4];
#pragma unroll
  for (int d = 0; d < 4; ++d)
#pragma unroll
    for (int r = 0; r < 16; ++r) o[d][r] = 0.f;
  float m2 = -1e30f, lp = 0.f;

  const int ntiles = (qbase + 128) >> 6;

  stageKV(0, smem);
  if (ntiles > 1) stageKV(64, smem + 32768);

  for (int tile = 0; tile < ntiles; ++tile) {
    const int kv0 = tile << 6;
    if (tile < ntiles - 1) {
      asm volatile("s_waitcnt vmcnt(8)\n\ts_barrier" ::: "memory");
    } else {
      asm volatile("s_waitcnt vmcnt(0)\n\ts_barrier" ::: "memory");
    }
    const char* Kl = smem + (size_t)(tile & 1) * 32768;
    const char* Vl = Kl + 16384;

    // ---- S^T = K . Q : K fragments from LDS (16-deep swz) ----
    f32x16 st[2];
#pragma unroll
    for (int tt = 0; tt < 2; ++tt)
#pragma unroll
      for (int r = 0; r < 16; ++r) st[tt][r] = 0.f;
    __builtin_amdgcn_s_setprio(1);
#pragma unroll
    for (int tt = 0; tt < 2; ++tt) {
      const char* krow = Kl + (tt * 32 + q5) * 256;
      const int swz = (q5 & 15) << 4;     // (tt*32+q5)&15 == q5&15
#pragma unroll
      for (int kb = 0; kb < 8; ++kb) {
        s16x8 ka = *(const s16x8*)(krow + ((kb * 32 + h5 * 16) ^ swz));
        st[tt] = __builtin_amdgcn_mfma_f32_32x32x16_bf16(ka, qb[kb], st[tt], 0, 0, 0);
      }
    }
    __builtin_amdgcn_s_setprio(0);

    // ---- mask (diag tiles only) + per-lane max ----
    const bool needmask = (kv0 + 63 > qrow0);
    float pm = -1e30f;
    if (needmask) {
#pragma unroll
      for (int tt = 0; tt < 2; ++tt)
#pragma unroll
        for (int r = 0; r < 16; ++r) {
          int kvloc = (r & 3) + 8 * (r >> 2) + 4 * h5 + 32 * tt;
          float v = st[tt][r];
          if (kv0 + kvloc > q_abs) v = -1e30f;
          st[tt][r] = v;
          pm = fmaxf(pm, v);
        }
    } else {
#pragma unroll
      for (int tt = 0; tt < 2; ++tt)
#pragma unroll
        for (int r = 0; r < 16; ++r) pm = fmaxf(pm, st[tt][r]);
    }

    // ---- deferred-max: vote only; rescale = scalar alpha per lane ----
    if (__any(pm - m2 > 8.0f)) {
      float tm = fmaxf(pm, __shfl_xor(pm, 32));
      float mn = fmaxf(m2, tm);
      float alpha = exp2f(m2 - mn);
      m2 = mn; lp *= alpha;
#pragma unroll
      for (int d = 0; d < 4; ++d)
#pragma unroll
        for (int r = 0; r < 16; ++r) o[d][r] *= alpha;
    }

    // ---- exp2 + pack + partner exchange, per-tt (short live ranges) ----
    s16x8 pb[2][2];
#pragma unroll
    for (int tt = 0; tt < 2; ++tt) {
      u32 pk[8], sw[8];
      float acc = 0.f;
#pragma unroll
      for (int i = 0; i < 8; ++i) {
        float e0 = exp2f(st[tt][2 * i]     - m2);
        float e1 = exp2f(st[tt][2 * i + 1] - m2);
        acc += e0 + e1;
        pk[i] = (u32)f2bf(e0) | ((u32)f2bf(e1) << 16);
      }
      lp += acc;
#pragma unroll
      for (int i = 0; i < 8; ++i)
        sw[i] = (u32)__shfl_xor((int)pk[i], 32);
#pragma unroll
      for (int kv2 = 0; kv2 < 2; ++kv2) {
        int i0 = kv2 * 4;
        u32x4 tmp;
        tmp[0] = h5 ? sw[i0 + 2] : pk[i0];
        tmp[1] = h5 ? sw[i0 + 3] : pk[i0 + 1];
        tmp[2] = h5 ? pk[i0 + 2] : sw[i0];
        tmp[3] = h5 ? pk[i0 + 3] : sw[i0 + 1];
        pb[tt][kv2] = __builtin_bit_cast(s16x8, tmp);
      }
    }

    // ---- O^T += V^T . P^T : V from folded LDS tile (16-deep swz) ----
    __builtin_amdgcn_s_setprio(1);
#pragma unroll
    for (int d = 0; d < 4; ++d) {
      const char* vrow = Vl + (((d & 1) * 32 + q5) * 256);
      const int vbase = (d >> 1) * 128;
      const int swz = (q5 & 15) << 4;     // pr&15 == q5&15
#pragma unroll
      for (int tt = 0; tt < 2; ++tt)
#pragma unroll
        for (int kv2 = 0; kv2 < 2; ++kv2) {
          s16x8 va = *(const s16x8*)(vrow + ((vbase + tt * 64 + kv2 * 32 + h5 * 16) ^ swz));
          o[d] = __builtin_amdgcn_mfma_f32_32x32x16_bf16(va, pb[tt][kv2], o[d], 0, 0, 0);
        }
    }
    __builtin_amdgcn_s_setprio(0);

    // ---- buffer free: drain LDS reads, then stage tile+2 into it ----
    asm volatile("s_waitcnt lgkmcnt(0)\n\ts_barrier" ::: "memory");
    if (tile + 2 < ntiles)
      stageKV((tile + 2) * 64, smem + (size_t)(tile & 1) * 32768);
  }

  // ---- finalize: one partner-sum shuffle, swizzled LDS repack, store ----
  float lt = lp + __shfl_xor(lp, 32);
  float inv = 1.0f / lt;
  __syncthreads();
  char* Olw = smem + w * 8192;   // 32 rows x 256 B per wave
#pragma unroll
  for (int d4 = 0; d4 < 4; ++d4)
#pragma unroll
    for (int r = 0; r < 16; ++r) {
      int dd = d4 * 32 + (r & 3) + 8 * (r >> 2) + 4 * h5;
      *(u16*)(Olw + q5 * 256 + ((dd * 2) ^ ((q5 & 7) << 4))) = f2bf(o[d4][r] * inv);
    }
  __syncthreads();
  const int h = bh & 15;
#pragma unroll
  for (int c = 0; c < 8; ++c) {
    int chunk = c * 256 + t;
    int row = chunk >> 4, sl = chunk & 15;
    u16x8 v = *(const u16x8*)(smem + row * 256 + ((sl * 16) ^ ((row & 7) << 4)));
    *(u16x8*)(AO + ((size_t)(b * 2048 + qbase + row)) * 2048 + h * 128 + sl * 8) = v;
  }
}

// ---------------------------------------------------------------------------
extern "C" void kernel_launch(void* const* d_in, const int* in_sizes, int n_in,
                              void* d_out, int out_size, void* d_ws, size_t ws_size,
                              hipStream_t stream)
{
  const float* x  = (const float*)d_in[0];
  const float* Wq = (const float*)d_in[1];
  const float* Wk = (const float*)d_in[2];
  const float* Wv = (const float*)d_in[3];
  const float* Wo = (const float*)d_in[4];
  const int*  pos = (const int*)d_in[5];

  char* ws = (char*)d_ws;
  const size_t MB32 = 33554432;
  u16* Qh = (u16*)(ws);
  u16* Kh = (u16*)(ws + MB32);
  u16* Vt = (u16*)(ws + 2 * MB32);

  dim3 blk(256);

  if (ws_size >= (size_t)167772160) {
    u16* xb = (u16*)(ws + 3 * MB32);   // 32 MiB; AO aliases this after x consumed
    u16* Wb = (u16*)(ws + 4 * MB32);   // Wq|Wk|Wv|Wo bf16, 8 MiB each
    u16* AO = xb;
    convert_kernel<<<2048, blk, 0, stream>>>(x, Wq, Wk, Wv, Wo, xb, Wb);
    gemm256<0, 24><<<768, 512, 0, stream>>>(xb, Wb, Qh, Kh, Vt, nullptr, pos);
    attn_kernel<<<1024, blk, 0, stream>>>(Qh, Kh, Vt, pos, AO);
    gemm256<1, 8><<<256, 512, 0, stream>>>(AO, Wb + 3 * 4194304, nullptr, nullptr, nullptr,
                                           (float*)d_out, pos);
  } else {
    u16* AO = (u16*)(ws + 3 * MB32);
    dim3 gg(16, 64);
    gemm_nt<0, 0, 0><<<gg, blk, 0, stream>>>(x, Wq, Qh);
    gemm_nt<0, 0, 0><<<gg, blk, 0, stream>>>(x, Wk, Kh);
    gemm_nt<0, 0, 1><<<gg, blk, 0, stream>>>(x, Wv, Vt);
    rope_k_kernel<<<2048, blk, 0, stream>>>(Kh, pos);
    attn_kernel<<<1024, blk, 0, stream>>>(Qh, Kh, Vt, pos, AO);
    gemm_nt<1, 0, 2><<<gg, blk, 0, stream>>>(AO, Wo, d_out);
  }
}

// Round 22
// 440.656 us; speedup vs baseline: 1.0007x; 1.0007x over previous
//
#include <hip/hip_runtime.h>

typedef unsigned int   u32;
typedef unsigned short u16;
typedef float f32x4  __attribute__((ext_vector_type(4)));
typedef float f32x16 __attribute__((ext_vector_type(16)));
typedef short s16x8  __attribute__((ext_vector_type(8)));
typedef u16   u16x4  __attribute__((ext_vector_type(4)));
typedef u16   u16x8  __attribute__((ext_vector_type(8)));
typedef u32   u32x4  __attribute__((ext_vector_type(4)));

#define DEVI __device__ __forceinline__

DEVI u16 f2bf(float f) {
  u32 u = __builtin_bit_cast(u32, f);
  u = (u + 0x7fffu + ((u >> 16) & 1u)) >> 16;
  return (u16)u;
}
DEVI float bf2f(u16 h) { u32 u = (u32)h << 16; return __builtin_bit_cast(float, u); }

DEVI void gload_lds16(const void* g, void* l) {
  __builtin_amdgcn_global_load_lds(
      (const __attribute__((address_space(1))) void*)g,
      (__attribute__((address_space(3))) void*)l, 16, 0, 0);
}

// ---------------------------------------------------------------------------
// fp32 -> bf16 pre-conversion of x and the four W matrices.
// ---------------------------------------------------------------------------
__global__ __launch_bounds__(256)
void convert_kernel(const float* __restrict__ x, const float* __restrict__ Wq,
                    const float* __restrict__ Wk, const float* __restrict__ Wv,
                    const float* __restrict__ Wo, u16* __restrict__ xb, u16* __restrict__ Wb)
{
  const int NX = 1 << 21;               // x vec8 chunks
  const int NT = NX + (1 << 21);        // + 4 * 2^19 W chunks
  for (int idx = blockIdx.x * 256 + threadIdx.x; idx < NT; idx += gridDim.x * 256) {
    const float* src; u16* dst; size_t off;
    if (idx < NX) { src = x; dst = xb; off = (size_t)idx * 8; }
    else {
      int i2 = idx - NX;
      int wsel = i2 >> 19, r = i2 & ((1 << 19) - 1);
      src = (wsel == 0) ? Wq : (wsel == 1) ? Wk : (wsel == 2) ? Wv : Wo;
      dst = Wb + (size_t)wsel * 4194304;
      off = (size_t)r * 8;
    }
    float4 a = *(const float4*)(src + off), b = *(const float4*)(src + off + 4);
    u16x8 o;
    o[0] = f2bf(a.x); o[1] = f2bf(a.y); o[2] = f2bf(a.z); o[3] = f2bf(a.w);
    o[4] = f2bf(b.x); o[5] = f2bf(b.y); o[6] = f2bf(b.z); o[7] = f2bf(b.w);
    *(u16x8*)(dst + off) = o;
  }
}

// ---------------------------------------------------------------------------
// 256x256 tile GEMM, counted-vmcnt double-buffered, split-kk (R19) +
// 4x4 super-tile block ordering (R20 mapping: gx = g%GX, gy = g/GX).
// EPI 0 / wsel==1 fuses K-RoPE on the f32 accumulator via fast
// __sinf/__cosf + shfl_xor(1) pair exchange (R21b, kept).
// ---------------------------------------------------------------------------
template<int EPI, int NBX>
__global__ __launch_bounds__(512, 2)
void gemm256(const u16* __restrict__ Ab, const u16* __restrict__ Bb,
             u16* __restrict__ Qh, u16* __restrict__ Kh, u16* __restrict__ Vt,
             float* __restrict__ Of, const int* __restrict__ pos)
{
  constexpr int K  = 2048;
  constexpr int NTILE = K / 64;          // 32
  constexpr int GX = NBX / 4;
  __shared__ __attribute__((aligned(16))) char smem[131072];

  const int t = threadIdx.x;
  const int lane = t & 63, w = t >> 6;
  const int lo = lane & 15, hi = lane >> 4;
  const int wr = w >> 2, wc = w & 3;

  const int nwg = gridDim.x;
  const int cpx = nwg >> 3;
  const int sbid = (blockIdx.x & 7) * cpx + (blockIdx.x >> 3);
  const int g = sbid >> 4, l = sbid & 15;           // 4x4 super-tile (R20)
  const int bx = (g % GX) * 4 + (l & 3);
  const int by = (g / GX) * 4 + (l >> 2);
  const int m0 = by * 256, n0 = bx * 256;

  auto stage = [&](const u16* gbase, char* lds) {
#pragma unroll
    for (int j = 0; j < 4; ++j) {
      int chunk = j * 512 + w * 64 + lane;
      int row = chunk >> 3, cc = chunk & 7;
      const u16* g2 = gbase + (size_t)row * K + ((cc ^ (row & 7)) * 8);
      gload_lds16(g2, lds + (size_t)(j * 512 + w * 64) * 16);
    }
  };

  f32x4 zero = {0.f, 0.f, 0.f, 0.f};
  f32x4 acc[8][4];
#pragma unroll
  for (int i = 0; i < 8; ++i)
#pragma unroll
    for (int j = 0; j < 4; ++j) acc[i][j] = zero;

  const u16* Abase = Ab + (size_t)m0 * K;
  const u16* Bbase = Bb + (size_t)n0 * K;

  stage(Abase + 0 * 64, smem);
  stage(Bbase + 0 * 64, smem + 32768);
  stage(Abase + 1 * 64, smem + 65536);
  stage(Bbase + 1 * 64, smem + 65536 + 32768);

  for (int tt = 0; tt < NTILE; ++tt) {
    if (tt < NTILE - 1) {
      asm volatile("s_waitcnt vmcnt(8)\n\ts_barrier" ::: "memory");
    } else {
      asm volatile("s_waitcnt vmcnt(0)\n\ts_barrier" ::: "memory");
    }
    const char* Alp = smem + (size_t)(tt & 1) * 65536;
    const char* Blp = Alp + 32768;

    // ---- kk = 0: reads then pure-register MFMA cluster ----
    s16x8 af0[8], bf0[4];
#pragma unroll
    for (int i = 0; i < 8; ++i) {
      int ra = wr * 128 + i * 16 + lo;
      af0[i] = *(const s16x8*)(Alp + ra * 128 + ((hi * 16) ^ ((ra & 7) << 4)));
    }
#pragma unroll
    for (int j = 0; j < 4; ++j) {
      int rb = wc * 64 + j * 16 + lo;
      bf0[j] = *(const s16x8*)(Blp + rb * 128 + ((hi * 16) ^ ((rb & 7) << 4)));
    }
    __builtin_amdgcn_s_setprio(1);
#pragma unroll
    for (int i = 0; i < 8; ++i)
#pragma unroll
      for (int j = 0; j < 4; ++j)
        acc[i][j] = __builtin_amdgcn_mfma_f32_16x16x32_bf16(af0[i], bf0[j], acc[i][j], 0, 0, 0);
    __builtin_amdgcn_s_setprio(0);

    // ---- kk = 1 reads (overlap kk0 MFMA tail) ----
    s16x8 af1[8], bf1[4];
#pragma unroll
    for (int i = 0; i < 8; ++i) {
      int ra = wr * 128 + i * 16 + lo;
      af1[i] = *(const s16x8*)(Alp + ra * 128 + (((4 + hi) * 16) ^ ((ra & 7) << 4)));
    }
#pragma unroll
    for (int j = 0; j < 4; ++j) {
      int rb = wc * 64 + j * 16 + lo;
      bf1[j] = *(const s16x8*)(Blp + rb * 128 + (((4 + hi) * 16) ^ ((rb & 7) << 4)));
    }
    // all waves done reading buf[tt&1]; buffer dead -> stage before kk1 MFMA
    asm volatile("s_waitcnt lgkmcnt(0)\n\ts_barrier" ::: "memory");
    if (tt + 2 < NTILE) {
      char* dst = smem + (size_t)(tt & 1) * 65536;
      stage(Abase + (tt + 2) * 64, dst);
      stage(Bbase + (tt + 2) * 64, dst + 32768);
    }
    __builtin_amdgcn_s_setprio(1);
#pragma unroll
    for (int i = 0; i < 8; ++i)
#pragma unroll
      for (int j = 0; j < 4; ++j)
        acc[i][j] = __builtin_amdgcn_mfma_f32_16x16x32_bf16(af1[i], bf1[j], acc[i][j], 0, 0, 0);
    __builtin_amdgcn_s_setprio(0);
  }

  const int mb = m0 + wr * 128;
  const int nb = n0 + wc * 64;
  if (EPI == 0) {
    const int wsel = n0 >> 11;
    u16* Out = (wsel == 0) ? Qh : (wsel == 1) ? Kh : Vt;
    const float CF = -0.20762050593046014f;  // -log2(10000)/64
#pragma unroll
    for (int i = 0; i < 8; ++i) {
      int m = mb + i * 16 + hi * 4;
      int b = m >> 11, s0 = m & 2047;
#pragma unroll
      for (int j = 0; j < 4; ++j) {
        int nn = (nb + j * 16 + lo) & 2047;
        int h = nn >> 7, d = nn & 127;
        if (wsel == 0) {
#pragma unroll
          for (int r = 0; r < 4; ++r)
            Out[((size_t)((b * 16 + h) * 2048) + s0 + r) * 128 + d] = f2bf(acc[i][j][r]);
        } else if (wsel == 1) {
          // fused K-RoPE on f32 acc; fast sin/cos (no scratch path)
          float fr = exp2f(CF * (float)(d >> 1));
#pragma unroll
          for (int r = 0; r < 4; ++r) {
            float own = acc[i][j][r];
            float oth = __shfl_xor(own, 1, 64);
            float p = (float)pos[(b << 11) + s0 + r];
            float ang = p * fr;
            float cs = __cosf(ang), sn = __sinf(ang);
            float v = (lo & 1) ? (oth * sn + own * cs) : (own * cs - oth * sn);
            Out[((size_t)((b * 16 + h) * 2048) + s0 + r) * 128 + d] = f2bf(v);
          }
        } else {
          u16x4 v;
#pragma unroll
          for (int r = 0; r < 4; ++r) v[r] = f2bf(acc[i][j][r]);
          *(u16x4*)(Out + ((size_t)(b * 16 + h) * 128 + d) * 2048 + s0) = v;
        }
      }
    }
  } else {
#pragma unroll
    for (int i = 0; i < 8; ++i)
#pragma unroll
      for (int j = 0; j < 4; ++j) {
        int n = nb + j * 16 + lo;
#pragma unroll
        for (int r = 0; r < 4; ++r)
          Of[(size_t)(mb + i * 16 + hi * 4 + r) * 2048 + n] = acc[i][j][r];
      }
  }
}

// ---------------------------------------------------------------------------
// Legacy 128^2 GEMM (fallback path only)
// ---------------------------------------------------------------------------
template<int AM, int WM, int EPI>
__global__ __launch_bounds__(256, 2)
void gemm_nt(const void* __restrict__ Ap, const void* __restrict__ Wp, void* __restrict__ Cp)
{
  constexpr int K = 2048;
  __shared__ __attribute__((aligned(16))) u16 Al[128 * 64];
  __shared__ __attribute__((aligned(16))) u16 Bl[128 * 64];

  const int t = threadIdx.x;
  const int lane = t & 63, w = t >> 6;
  const int lo = lane & 15, hi = lane >> 4;
  const int wm = w >> 1, wn = w & 1;
  const int m0 = blockIdx.y * 128, n0 = blockIdx.x * 128;

  f32x4 zero = {0.f, 0.f, 0.f, 0.f};
  f32x4 acc[4][4];
#pragma unroll
  for (int i = 0; i < 4; ++i)
#pragma unroll
    for (int j = 0; j < 4; ++j) acc[i][j] = zero;

  for (int k0 = 0; k0 < K; k0 += 64) {
    __syncthreads();
    if (AM == 1) {
      const u16* A = (const u16*)Ap;
#pragma unroll
      for (int j = 0; j < 4; ++j) {
        int row = (w * 4 + j) * 8 + (lane >> 3);
        const u16* g = A + (size_t)(m0 + row) * K + k0 + (lane & 7) * 8;
        gload_lds16(g, (char*)Al + (w * 4 + j) * 1024);
      }
    } else {
      const float* A = (const float*)Ap;
#pragma unroll
      for (int c = 0; c < 2; ++c) {
        int chunk = c * 256 + t;
        int row = chunk >> 2, q = chunk & 3;
        const float4* g = reinterpret_cast<const float4*>(A + (size_t)(m0 + row) * K + k0 + q * 16);
        float4 v0 = g[0], v1 = g[1], v2 = g[2], v3 = g[3];
        u16x8 o0, o1;
        o0[0] = f2bf(v0.x); o0[1] = f2bf(v0.y); o0[2] = f2bf(v0.z); o0[3] = f2bf(v0.w);
        o0[4] = f2bf(v1.x); o0[5] = f2bf(v1.y); o0[6] = f2bf(v1.z); o0[7] = f2bf(v1.w);
        o1[0] = f2bf(v2.x); o1[1] = f2bf(v2.y); o1[2] = f2bf(v2.z); o1[3] = f2bf(v2.w);
        o1[4] = f2bf(v3.x); o1[5] = f2bf(v3.y); o1[6] = f2bf(v3.z); o1[7] = f2bf(v3.w);
        int swz = (row & 7) << 4;
        char* base = (char*)Al + row * 128;
        *(u16x8*)(base + ((q * 32)      ^ swz)) = o0;
        *(u16x8*)(base + ((q * 32 + 16) ^ swz)) = o1;
      }
    }
    if (WM == 1) {
      const u16* B = (const u16*)Wp;
#pragma unroll
      for (int j = 0; j < 4; ++j) {
        int row = (w * 4 + j) * 8 + (lane >> 3);
        const u16* g = B + (size_t)(n0 + row) * K + k0 + (lane & 7) * 8;
        gload_lds16(g, (char*)Bl + (w * 4 + j) * 1024);
      }
    } else {
      const float* B = (const float*)Wp;
#pragma unroll
      for (int c = 0; c < 2; ++c) {
        int chunk = c * 256 + t;
        int row = chunk >> 2, q = chunk & 3;
        const float4* g = reinterpret_cast<const float4*>(B + (size_t)(n0 + row) * K + k0 + q * 16);
        float4 v0 = g[0], v1 = g[1], v2 = g[2], v3 = g[3];
        u16x8 o0, o1;
        o0[0] = f2bf(v0.x); o0[1] = f2bf(v0.y); o0[2] = f2bf(v0.z); o0[3] = f2bf(v0.w);
        o0[4] = f2bf(v1.x); o0[5] = f2bf(v1.y); o0[6] = f2bf(v1.z); o0[7] = f2bf(v1.w);
        o1[0] = f2bf(v2.x); o1[1] = f2bf(v2.y); o1[2] = f2bf(v2.z); o1[3] = f2bf(v2.w);
        o1[4] = f2bf(v3.x); o1[5] = f2bf(v3.y); o1[6] = f2bf(v3.z); o1[7] = f2bf(v3.w);
        int swz = (row & 7) << 4;
        char* base = (char*)Bl + row * 128;
        *(u16x8*)(base + ((q * 32)      ^ swz)) = o0;
        *(u16x8*)(base + ((q * 32 + 16) ^ swz)) = o1;
      }
    }
    __syncthreads();
#pragma unroll
    for (int kk = 0; kk < 2; ++kk) {
      s16x8 af[4], bfr[4];
#pragma unroll
      for (int i = 0; i < 4; ++i) {
        int ra = wm * 64 + i * 16 + lo;
        int ca = (kk * 4 + hi) * 16; if (AM != 1) ca ^= (ra & 7) << 4;
        af[i]  = *(const s16x8*)((const char*)Al + ra * 128 + ca);
        int rb = wn * 64 + i * 16 + lo;
        int cb = (kk * 4 + hi) * 16; if (WM != 1) cb ^= (rb & 7) << 4;
        bfr[i] = *(const s16x8*)((const char*)Bl + rb * 128 + cb);
      }
#pragma unroll
      for (int i = 0; i < 4; ++i)
#pragma unroll
        for (int j = 0; j < 4; ++j)
          acc[i][j] = __builtin_amdgcn_mfma_f32_16x16x32_bf16(af[i], bfr[j], acc[i][j], 0, 0, 0);
    }
  }

  const int mb = m0 + wm * 64, nb = n0 + wn * 64;
  if (EPI == 0) {
    u16* Out = (u16*)Cp;
#pragma unroll
    for (int i = 0; i < 4; ++i)
#pragma unroll
      for (int j = 0; j < 4; ++j) {
        int n = nb + j * 16 + lo;
        int h = n >> 7, d = n & 127;
#pragma unroll
        for (int r = 0; r < 4; ++r) {
          int m = mb + i * 16 + hi * 4 + r;
          int b = m >> 11, s = m & 2047;
          Out[((size_t)((b * 16 + h) * 2048 + s)) * 128 + d] = f2bf(acc[i][j][r]);
        }
      }
  } else if (EPI == 1) {
    u16* Out = (u16*)Cp;
#pragma unroll
    for (int i = 0; i < 4; ++i)
#pragma unroll
      for (int j = 0; j < 4; ++j) {
        int n = nb + j * 16 + lo;
        int h = n >> 7, d = n & 127;
        int m = mb + i * 16 + hi * 4;
        int b = m >> 11, s = m & 2047;
        u16x4 v;
#pragma unroll
        for (int r = 0; r < 4; ++r) v[r] = f2bf(acc[i][j][r]);
        *(u16x4*)(Out + ((size_t)((b * 16 + h) * 128 + d)) * 2048 + s) = v;
      }
  } else {
    float* Out = (float*)Cp;
#pragma unroll
    for (int i = 0; i < 4; ++i)
#pragma unroll
      for (int j = 0; j < 4; ++j) {
        int n = nb + j * 16 + lo;
#pragma unroll
        for (int r = 0; r < 4; ++r) {
          int m = mb + i * 16 + hi * 4 + r;
          Out[(size_t)m * 2048 + n] = acc[i][j][r];
        }
      }
  }
}

// ---------------------------------------------------------------------------
// RoPE in-place on K only (fallback path only; fast path fuses into gemm)
// ---------------------------------------------------------------------------
__global__ __launch_bounds__(256)
void rope_k_kernel(u16* __restrict__ Kh, const int* __restrict__ pos)
{
  const int NP = 4 * 16 * 2048 * 64; // pairs
  const float C = -0.20762050593046014f; // -log2(10000)/64
  for (int idx = blockIdx.x * 256 + threadIdx.x; idx < NP; idx += gridDim.x * 256) {
    int i = idx & 63;
    int srow = idx >> 6;          // bh*2048 + s
    int s = srow & 2047;
    int b = srow >> 15;
    int p = pos[(b << 11) + s];
    float ang = (float)p * exp2f(C * (float)i);
    float sn, cs;
    sincosf(ang, &sn, &cs);
    u32* kp = (u32*)Kh + (size_t)srow * 64 + i;
    u32 v = *kp;
    float x1 = bf2f((u16)(v & 0xffffu)), x2 = bf2f((u16)(v >> 16));
    *kp = (u32)f2bf(x1 * cs - x2 * sn) | ((u32)f2bf(x1 * sn + x2 * cs) << 16);
  }
}

// ---------------------------------------------------------------------------
// Causal flash attention (R18 form, unchanged): swapped-operand 32x32 +
// cooperative double-buffered K/V LDS staging + 16-deep XOR swizzles.
// ---------------------------------------------------------------------------
__global__ __launch_bounds__(256, 2)
void attn_kernel(const u16* __restrict__ Qh, const u16* __restrict__ Kh,
                 const u16* __restrict__ Vt, const int* __restrict__ pos,
                 u16* __restrict__ AO)
{
  __shared__ __attribute__((aligned(16))) char smem[65536];

  const int t = threadIdx.x, lane = t & 63, w = t >> 6;
  const int q5 = lane & 31, h5 = lane >> 5;
  const int bid = blockIdx.x;
  const int bh = (((bid >> 3) & 7) << 3) | (bid & 7);   // XCD-slot pinned
  const int qt = bid >> 6;                  // 0..15
  const int qbase = (15 - qt) * 128;        // heavy tiles dispatch first
  const int b = bh >> 4;
  const int qrow0 = qbase + w * 32;
  const int q_abs = qrow0 + q5;

  const u16* Kb = Kh + (size_t)bh * 2048 * 128;   // [2048][128]
  const u16* Vb = Vt + (size_t)bh * 128 * 2048;   // [128][2048]

  auto stageKV = [&](int kv0, char* dst) {
#pragma unroll
    for (int j = 0; j < 4; ++j) {           // K: 1024 16B-chunks, 16-deep swz
      int chunk = j * 256 + w * 64 + lane;
      int row = chunk >> 4, cc = chunk & 15;
      const u16* g = Kb + (size_t)(kv0 + row) * 128 + ((cc ^ (row & 15)) * 8);
      gload_lds16(g, dst + (size_t)chunk * 16);
    }
#pragma unroll
    for (int j = 0; j < 4; ++j) {           // V: folded 64x256B, 16-deep swz
      int chunk = j * 256 + w * 64 + lane;
      int pr = chunk >> 4, o16 = chunk & 15;
      int orig = o16 ^ (pr & 15);
      int grow = ((orig >> 3) << 6) + pr;   // logical row = half*64 + pr
      const u16* g = Vb + (size_t)grow * 2048 + kv0 + ((orig & 7) * 8);
      gload_lds16(g, dst + 16384 + (size_t)chunk * 16);
    }
  };

  // ---- Q fragments with fused RoPE; softmax scale folded (registers) ----
  s16x8 qb[8];
  const float CF = -0.20762050593046014f;   // -log2(10000)/64
  const float QSCALE = 0.08838834764831845f * 1.4426950408889634f;
  {
    float p = (float)pos[(b << 11) + q_abs];
    const u16* qrow = Qh + ((size_t)bh * 2048 + q_abs) * 128;
#pragma unroll
    for (int kb = 0; kb < 8; ++kb) {
      s16x8 raw = *reinterpret_cast<const s16x8*>(qrow + kb * 16 + h5 * 8);
      s16x8 out;
#pragma unroll
      for (int u = 0; u < 4; ++u) {
        float x1 = bf2f((u16)raw[2 * u]), x2 = bf2f((u16)raw[2 * u + 1]);
        float ang = p * exp2f(CF * (float)(kb * 8 + h5 * 4 + u));
        float sn, cs; sincosf(ang, &sn, &cs);
        sn *= QSCALE; cs *= QSCALE;
        out[2 * u]     = (short)f2bf(x1 * cs - x2 * sn);
        out[2 * u + 1] = (short)f2bf(x1 * sn + x2 * cs);
      }
      qb[kb] = out;
    }
  }

  f32x16 o[4];
#pragma unroll
  for (int d = 0; d < 4; ++d)
#pragma unroll
    for (int r = 0; r < 16; ++r) o[d][r] = 0.f;
  float m2 = -1e30f, lp = 0.f;

  const int ntiles = (qbase + 128) >> 6;

  stageKV(0, smem);
  if (ntiles > 1) stageKV(64, smem + 32768);

  for (int tile = 0; tile < ntiles; ++tile) {
    const int kv0 = tile << 6;
    if (tile < ntiles - 1) {
      asm volatile("s_waitcnt vmcnt(8)\n\ts_barrier" ::: "memory");
    } else {
      asm volatile("s_waitcnt vmcnt(0)\n\ts_barrier" ::: "memory");
    }
    const char* Kl = smem + (size_t)(tile & 1) * 32768;
    const char* Vl = Kl + 16384;

    // ---- S^T = K . Q : K fragments from LDS (16-deep swz) ----
    f32x16 st[2];
#pragma unroll
    for (int tt = 0; tt < 2; ++tt)
#pragma unroll
      for (int r = 0; r < 16; ++r) st[tt][r] = 0.f;
    __builtin_amdgcn_s_setprio(1);
#pragma unroll
    for (int tt = 0; tt < 2; ++tt) {
      const char* krow = Kl + (tt * 32 + q5) * 256;
      const int swz = (q5 & 15) << 4;     // (tt*32+q5)&15 == q5&15
#pragma unroll
      for (int kb = 0; kb < 8; ++kb) {
        s16x8 ka = *(const s16x8*)(krow + ((kb * 32 + h5 * 16) ^ swz));
        st[tt] = __builtin_amdgcn_mfma_f32_32x32x16_bf16(ka, qb[kb], st[tt], 0, 0, 0);
      }
    }
    __builtin_amdgcn_s_setprio(0);

    // ---- mask (diag tiles only) + per-lane max ----
    const bool needmask = (kv0 + 63 > qrow0);
    float pm = -1e30f;
    if (needmask) {
#pragma unroll
      for (int tt = 0; tt < 2; ++tt)
#pragma unroll
        for (int r = 0; r < 16; ++r) {
          int kvloc = (r & 3) + 8 * (r >> 2) + 4 * h5 + 32 * tt;
          float v = st[tt][r];
          if (kv0 + kvloc > q_abs) v = -1e30f;
          st[tt][r] = v;
          pm = fmaxf(pm, v);
        }
    } else {
#pragma unroll
      for (int tt = 0; tt < 2; ++tt)
#pragma unroll
        for (int r = 0; r < 16; ++r) pm = fmaxf(pm, st[tt][r]);
    }

    // ---- deferred-max: vote only; rescale = scalar alpha per lane ----
    if (__any(pm - m2 > 8.0f)) {
      float tm = fmaxf(pm, __shfl_xor(pm, 32));
      float mn = fmaxf(m2, tm);
      float alpha = exp2f(m2 - mn);
      m2 = mn; lp *= alpha;
#pragma unroll
      for (int d = 0; d < 4; ++d)
#pragma unroll
        for (int r = 0; r < 16; ++r) o[d][r] *= alpha;
    }

    // ---- exp2 + pack + partner exchange, per-tt (short live ranges) ----
    s16x8 pb[2][2];
#pragma unroll
    for (int tt = 0; tt < 2; ++tt) {
      u32 pk[8], sw[8];
      float acc = 0.f;
#pragma unroll
      for (int i = 0; i < 8; ++i) {
        float e0 = exp2f(st[tt][2 * i]     - m2);
        float e1 = exp2f(st[tt][2 * i + 1] - m2);
        acc += e0 + e1;
        pk[i] = (u32)f2bf(e0) | ((u32)f2bf(e1) << 16);
      }
      lp += acc;
#pragma unroll
      for (int i = 0; i < 8; ++i)
        sw[i] = (u32)__shfl_xor((int)pk[i], 32);
#pragma unroll
      for (int kv2 = 0; kv2 < 2; ++kv2) {
        int i0 = kv2 * 4;
        u32x4 tmp;
        tmp[0] = h5 ? sw[i0 + 2] : pk[i0];
        tmp[1] = h5 ? sw[i0 + 3] : pk[i0 + 1];
        tmp[2] = h5 ? pk[i0 + 2] : sw[i0];
        tmp[3] = h5 ? pk[i0 + 3] : sw[i0 + 1];
        pb[tt][kv2] = __builtin_bit_cast(s16x8, tmp);
      }
    }

    // ---- O^T += V^T . P^T : V from folded LDS tile (16-deep swz) ----
    __builtin_amdgcn_s_setprio(1);
#pragma unroll
    for (int d = 0; d < 4; ++d) {
      const char* vrow = Vl + (((d & 1) * 32 + q5) * 256);
      const int vbase = (d >> 1) * 128;
      const int swz = (q5 & 15) << 4;     // pr&15 == q5&15
#pragma unroll
      for (int tt = 0; tt < 2; ++tt)
#pragma unroll
        for (int kv2 = 0; kv2 < 2; ++kv2) {
          s16x8 va = *(const s16x8*)(vrow + ((vbase + tt * 64 + kv2 * 32 + h5 * 16) ^ swz));
          o[d] = __builtin_amdgcn_mfma_f32_32x32x16_bf16(va, pb[tt][kv2], o[d], 0, 0, 0);
        }
    }
    __builtin_amdgcn_s_setprio(0);

    // ---- buffer free: drain LDS reads, then stage tile+2 into it ----
    asm volatile("s_waitcnt lgkmcnt(0)\n\ts_barrier" ::: "memory");
    if (tile + 2 < ntiles)
      stageKV((tile + 2) * 64, smem + (size_t)(tile & 1) * 32768);
  }

  // ---- finalize: one partner-sum shuffle, swizzled LDS repack, store ----
  float lt = lp + __shfl_xor(lp, 32);
  float inv = 1.0f / lt;
  __syncthreads();
  char* Olw = smem + w * 8192;   // 32 rows x 256 B per wave
#pragma unroll
  for (int d4 = 0; d4 < 4; ++d4)
#pragma unroll
    for (int r = 0; r < 16; ++r) {
      int dd = d4 * 32 + (r & 3) + 8 * (r >> 2) + 4 * h5;
      *(u16*)(Olw + q5 * 256 + ((dd * 2) ^ ((q5 & 7) << 4))) = f2bf(o[d4][r] * inv);
    }
  __syncthreads();
  const int h = bh & 15;
#pragma unroll
  for (int c = 0; c < 8; ++c) {
    int chunk = c * 256 + t;
    int row = chunk >> 4, sl = chunk & 15;
    u16x8 v = *(const u16x8*)(smem + row * 256 + ((sl * 16) ^ ((row & 7) << 4)));
    *(u16x8*)(AO + ((size_t)(b * 2048 + qbase + row)) * 2048 + h * 128 + sl * 8) = v;
  }
}

// ---------------------------------------------------------------------------
extern "C" void kernel_launch(void* const* d_in, const int* in_sizes, int n_in,
                              void* d_out, int out_size, void* d_ws, size_t ws_size,
                              hipStream_t stream)
{
  const float* x  = (const float*)d_in[0];
  const float* Wq = (const float*)d_in[1];
  const float* Wk = (const float*)d_in[2];
  const float* Wv = (const float*)d_in[3];
  const float* Wo = (const float*)d_in[4];
  const int*  pos = (const int*)d_in[5];

  char* ws = (char*)d_ws;
  const size_t MB32 = 33554432;
  u16* Qh = (u16*)(ws);
  u16* Kh = (u16*)(ws + MB32);
  u16* Vt = (u16*)(ws + 2 * MB32);

  dim3 blk(256);

  if (ws_size >= (size_t)167772160) {
    u16* xb = (u16*)(ws + 3 * MB32);   // 32 MiB; AO aliases this after x consumed
    u16* Wb = (u16*)(ws + 4 * MB32);   // Wq|Wk|Wv|Wo bf16, 8 MiB each
    u16* AO = xb;
    convert_kernel<<<2048, blk, 0, stream>>>(x, Wq, Wk, Wv, Wo, xb, Wb);
    gemm256<0, 24><<<768, 512, 0, stream>>>(xb, Wb, Qh, Kh, Vt, nullptr, pos);
    attn_kernel<<<1024, blk, 0, stream>>>(Qh, Kh, Vt, pos, AO);
    gemm256<1, 8><<<256, 512, 0, stream>>>(AO, Wb + 3 * 4194304, nullptr, nullptr, nullptr,
                                           (float*)d_out, pos);
  } else {
    u16* AO = (u16*)(ws + 3 * MB32);
    dim3 gg(16, 64);
    gemm_nt<0, 0, 0><<<gg, blk, 0, stream>>>(x, Wq, Qh);
    gemm_nt<0, 0, 0><<<gg, blk, 0, stream>>>(x, Wk, Kh);
    gemm_nt<0, 0, 1><<<gg, blk, 0, stream>>>(x, Wv, Vt);
    rope_k_kernel<<<2048, blk, 0, stream>>>(Kh, pos);
    attn_kernel<<<1024, blk, 0, stream>>>(Qh, Kh, Vt, pos, AO);
    gemm_nt<1, 0, 2><<<gg, blk, 0, stream>>>(AO, Wo, d_out);
  }
}

// Round 23
// 439.470 us; speedup vs baseline: 1.0034x; 1.0027x over previous
//
#include <hip/hip_runtime.h>

typedef unsigned int   u32;
typedef unsigned short u16;
typedef float f32x4  __attribute__((ext_vector_type(4)));
typedef float f32x16 __attribute__((ext_vector_type(16)));
typedef short s16x8  __attribute__((ext_vector_type(8)));
typedef u16   u16x4  __attribute__((ext_vector_type(4)));
typedef u16   u16x8  __attribute__((ext_vector_type(8)));
typedef u32   u32x4  __attribute__((ext_vector_type(4)));

#define DEVI __device__ __forceinline__

DEVI u16 f2bf(float f) {
  u32 u = __builtin_bit_cast(u32, f);
  u = (u + 0x7fffu + ((u >> 16) & 1u)) >> 16;
  return (u16)u;
}
DEVI float bf2f(u16 h) { u32 u = (u32)h << 16; return __builtin_bit_cast(float, u); }

DEVI void gload_lds16(const void* g, void* l) {
  __builtin_amdgcn_global_load_lds(
      (const __attribute__((address_space(1))) void*)g,
      (__attribute__((address_space(3))) void*)l, 16, 0, 0);
}

// ---------------------------------------------------------------------------
// fp32 -> bf16 pre-conversion of x and the four W matrices.
// ---------------------------------------------------------------------------
__global__ __launch_bounds__(256)
void convert_kernel(const float* __restrict__ x, const float* __restrict__ Wq,
                    const float* __restrict__ Wk, const float* __restrict__ Wv,
                    const float* __restrict__ Wo, u16* __restrict__ xb, u16* __restrict__ Wb)
{
  const int NX = 1 << 21;               // x vec8 chunks
  const int NT = NX + (1 << 21);        // + 4 * 2^19 W chunks
  for (int idx = blockIdx.x * 256 + threadIdx.x; idx < NT; idx += gridDim.x * 256) {
    const float* src; u16* dst; size_t off;
    if (idx < NX) { src = x; dst = xb; off = (size_t)idx * 8; }
    else {
      int i2 = idx - NX;
      int wsel = i2 >> 19, r = i2 & ((1 << 19) - 1);
      src = (wsel == 0) ? Wq : (wsel == 1) ? Wk : (wsel == 2) ? Wv : Wo;
      dst = Wb + (size_t)wsel * 4194304;
      off = (size_t)r * 8;
    }
    float4 a = *(const float4*)(src + off), b = *(const float4*)(src + off + 4);
    u16x8 o;
    o[0] = f2bf(a.x); o[1] = f2bf(a.y); o[2] = f2bf(a.z); o[3] = f2bf(a.w);
    o[4] = f2bf(b.x); o[5] = f2bf(b.y); o[6] = f2bf(b.z); o[7] = f2bf(b.w);
    *(u16x8*)(dst + off) = o;
  }
}

// ---------------------------------------------------------------------------
// 256x256 tile GEMM, counted-vmcnt double-buffered, split-kk (R19) +
// 4x4 super-tile block ordering for L2 locality (R20; bijective since
// nwg = 16 * (NBX/4) * 8). GX = NBX/4.
// ---------------------------------------------------------------------------
template<int EPI, int NBX>
__global__ __launch_bounds__(512, 2)
void gemm256(const u16* __restrict__ Ab, const u16* __restrict__ Bb,
             u16* __restrict__ Qh, u16* __restrict__ Kh, u16* __restrict__ Vt,
             float* __restrict__ Of)
{
  constexpr int K  = 2048;
  constexpr int NTILE = K / 64;          // 32
  constexpr int GX = NBX / 4;
  __shared__ __attribute__((aligned(16))) char smem[131072];

  const int t = threadIdx.x;
  const int lane = t & 63, w = t >> 6;
  const int lo = lane & 15, hi = lane >> 4;
  const int wr = w >> 2, wc = w & 3;

  const int nwg = gridDim.x;
  const int cpx = nwg >> 3;
  const int sbid = (blockIdx.x & 7) * cpx + (blockIdx.x >> 3);
  const int g = sbid >> 4, l = sbid & 15;           // 4x4 super-tile
  const int bx = (g % GX) * 4 + (l & 3);
  const int by = (g / GX) * 4 + (l >> 2);
  const int m0 = by * 256, n0 = bx * 256;

  auto stage = [&](const u16* gbase, char* lds) {
#pragma unroll
    for (int j = 0; j < 4; ++j) {
      int chunk = j * 512 + w * 64 + lane;
      int row = chunk >> 3, cc = chunk & 7;
      const u16* g2 = gbase + (size_t)row * K + ((cc ^ (row & 7)) * 8);
      gload_lds16(g2, lds + (size_t)(j * 512 + w * 64) * 16);
    }
  };

  f32x4 zero = {0.f, 0.f, 0.f, 0.f};
  f32x4 acc[8][4];
#pragma unroll
  for (int i = 0; i < 8; ++i)
#pragma unroll
    for (int j = 0; j < 4; ++j) acc[i][j] = zero;

  const u16* Abase = Ab + (size_t)m0 * K;
  const u16* Bbase = Bb + (size_t)n0 * K;

  stage(Abase + 0 * 64, smem);
  stage(Bbase + 0 * 64, smem + 32768);
  stage(Abase + 1 * 64, smem + 65536);
  stage(Bbase + 1 * 64, smem + 65536 + 32768);

  for (int tt = 0; tt < NTILE; ++tt) {
    if (tt < NTILE - 1) {
      asm volatile("s_waitcnt vmcnt(8)\n\ts_barrier" ::: "memory");
    } else {
      asm volatile("s_waitcnt vmcnt(0)\n\ts_barrier" ::: "memory");
    }
    const char* Alp = smem + (size_t)(tt & 1) * 65536;
    const char* Blp = Alp + 32768;

    // ---- kk = 0: reads then pure-register MFMA cluster ----
    s16x8 af0[8], bf0[4];
#pragma unroll
    for (int i = 0; i < 8; ++i) {
      int ra = wr * 128 + i * 16 + lo;
      af0[i] = *(const s16x8*)(Alp + ra * 128 + ((hi * 16) ^ ((ra & 7) << 4)));
    }
#pragma unroll
    for (int j = 0; j < 4; ++j) {
      int rb = wc * 64 + j * 16 + lo;
      bf0[j] = *(const s16x8*)(Blp + rb * 128 + ((hi * 16) ^ ((rb & 7) << 4)));
    }
    __builtin_amdgcn_s_setprio(1);
#pragma unroll
    for (int i = 0; i < 8; ++i)
#pragma unroll
      for (int j = 0; j < 4; ++j)
        acc[i][j] = __builtin_amdgcn_mfma_f32_16x16x32_bf16(af0[i], bf0[j], acc[i][j], 0, 0, 0);
    __builtin_amdgcn_s_setprio(0);

    // ---- kk = 1 reads (overlap kk0 MFMA tail) ----
    s16x8 af1[8], bf1[4];
#pragma unroll
    for (int i = 0; i < 8; ++i) {
      int ra = wr * 128 + i * 16 + lo;
      af1[i] = *(const s16x8*)(Alp + ra * 128 + (((4 + hi) * 16) ^ ((ra & 7) << 4)));
    }
#pragma unroll
    for (int j = 0; j < 4; ++j) {
      int rb = wc * 64 + j * 16 + lo;
      bf1[j] = *(const s16x8*)(Blp + rb * 128 + (((4 + hi) * 16) ^ ((rb & 7) << 4)));
    }
    // all waves done reading buf[tt&1]; buffer dead -> stage before kk1 MFMA
    asm volatile("s_waitcnt lgkmcnt(0)\n\ts_barrier" ::: "memory");
    if (tt + 2 < NTILE) {
      char* dst = smem + (size_t)(tt & 1) * 65536;
      stage(Abase + (tt + 2) * 64, dst);
      stage(Bbase + (tt + 2) * 64, dst + 32768);
    }
    __builtin_amdgcn_s_setprio(1);
#pragma unroll
    for (int i = 0; i < 8; ++i)
#pragma unroll
      for (int j = 0; j < 4; ++j)
        acc[i][j] = __builtin_amdgcn_mfma_f32_16x16x32_bf16(af1[i], bf1[j], acc[i][j], 0, 0, 0);
    __builtin_amdgcn_s_setprio(0);
  }

  const int mb = m0 + wr * 128;
  const int nb = n0 + wc * 64;
  if (EPI == 0) {
    const int wsel = n0 >> 11;
    u16* Out = (wsel == 0) ? Qh : (wsel == 1) ? Kh : Vt;
#pragma unroll
    for (int i = 0; i < 8; ++i) {
      int m = mb + i * 16 + hi * 4;
      int b = m >> 11, s0 = m & 2047;
#pragma unroll
      for (int j = 0; j < 4; ++j) {
        int nn = (nb + j * 16 + lo) & 2047;
        int h = nn >> 7, d = nn & 127;
        if (wsel < 2) {
#pragma unroll
          for (int r = 0; r < 4; ++r)
            Out[((size_t)((b * 16 + h) * 2048) + s0 + r) * 128 + d] = f2bf(acc[i][j][r]);
        } else {
          u16x4 v;
#pragma unroll
          for (int r = 0; r < 4; ++r) v[r] = f2bf(acc[i][j][r]);
          *(u16x4*)(Out + ((size_t)(b * 16 + h) * 128 + d) * 2048 + s0) = v;
        }
      }
    }
  } else {
#pragma unroll
    for (int i = 0; i < 8; ++i)
#pragma unroll
      for (int j = 0; j < 4; ++j) {
        int n = nb + j * 16 + lo;
#pragma unroll
        for (int r = 0; r < 4; ++r)
          Of[(size_t)(mb + i * 16 + hi * 4 + r) * 2048 + n] = acc[i][j][r];
      }
  }
}

// ---------------------------------------------------------------------------
// Legacy 128^2 GEMM (fallback path only)
// ---------------------------------------------------------------------------
template<int AM, int WM, int EPI>
__global__ __launch_bounds__(256, 2)
void gemm_nt(const void* __restrict__ Ap, const void* __restrict__ Wp, void* __restrict__ Cp)
{
  constexpr int K = 2048;
  __shared__ __attribute__((aligned(16))) u16 Al[128 * 64];
  __shared__ __attribute__((aligned(16))) u16 Bl[128 * 64];

  const int t = threadIdx.x;
  const int lane = t & 63, w = t >> 6;
  const int lo = lane & 15, hi = lane >> 4;
  const int wm = w >> 1, wn = w & 1;
  const int m0 = blockIdx.y * 128, n0 = blockIdx.x * 128;

  f32x4 zero = {0.f, 0.f, 0.f, 0.f};
  f32x4 acc[4][4];
#pragma unroll
  for (int i = 0; i < 4; ++i)
#pragma unroll
    for (int j = 0; j < 4; ++j) acc[i][j] = zero;

  for (int k0 = 0; k0 < K; k0 += 64) {
    __syncthreads();
    if (AM == 1) {
      const u16* A = (const u16*)Ap;
#pragma unroll
      for (int j = 0; j < 4; ++j) {
        int row = (w * 4 + j) * 8 + (lane >> 3);
        const u16* g = A + (size_t)(m0 + row) * K + k0 + (lane & 7) * 8;
        gload_lds16(g, (char*)Al + (w * 4 + j) * 1024);
      }
    } else {
      const float* A = (const float*)Ap;
#pragma unroll
      for (int c = 0; c < 2; ++c) {
        int chunk = c * 256 + t;
        int row = chunk >> 2, q = chunk & 3;
        const float4* g = reinterpret_cast<const float4*>(A + (size_t)(m0 + row) * K + k0 + q * 16);
        float4 v0 = g[0], v1 = g[1], v2 = g[2], v3 = g[3];
        u16x8 o0, o1;
        o0[0] = f2bf(v0.x); o0[1] = f2bf(v0.y); o0[2] = f2bf(v0.z); o0[3] = f2bf(v0.w);
        o0[4] = f2bf(v1.x); o0[5] = f2bf(v1.y); o0[6] = f2bf(v1.z); o0[7] = f2bf(v1.w);
        o1[0] = f2bf(v2.x); o1[1] = f2bf(v2.y); o1[2] = f2bf(v2.z); o1[3] = f2bf(v2.w);
        o1[4] = f2bf(v3.x); o1[5] = f2bf(v3.y); o1[6] = f2bf(v3.z); o1[7] = f2bf(v3.w);
        int swz = (row & 7) << 4;
        char* base = (char*)Al + row * 128;
        *(u16x8*)(base + ((q * 32)      ^ swz)) = o0;
        *(u16x8*)(base + ((q * 32 + 16) ^ swz)) = o1;
      }
    }
    if (WM == 1) {
      const u16* B = (const u16*)Wp;
#pragma unroll
      for (int j = 0; j < 4; ++j) {
        int row = (w * 4 + j) * 8 + (lane >> 3);
        const u16* g = B + (size_t)(n0 + row) * K + k0 + (lane & 7) * 8;
        gload_lds16(g, (char*)Bl + (w * 4 + j) * 1024);
      }
    } else {
      const float* B = (const float*)Wp;
#pragma unroll
      for (int c = 0; c < 2; ++c) {
        int chunk = c * 256 + t;
        int row = chunk >> 2, q = chunk & 3;
        const float4* g = reinterpret_cast<const float4*>(B + (size_t)(n0 + row) * K + k0 + q * 16);
        float4 v0 = g[0], v1 = g[1], v2 = g[2], v3 = g[3];
        u16x8 o0, o1;
        o0[0] = f2bf(v0.x); o0[1] = f2bf(v0.y); o0[2] = f2bf(v0.z); o0[3] = f2bf(v0.w);
        o0[4] = f2bf(v1.x); o0[5] = f2bf(v1.y); o0[6] = f2bf(v1.z); o0[7] = f2bf(v1.w);
        o1[0] = f2bf(v2.x); o1[1] = f2bf(v2.y); o1[2] = f2bf(v2.z); o1[3] = f2bf(v2.w);
        o1[4] = f2bf(v3.x); o1[5] = f2bf(v3.y); o1[6] = f2bf(v3.z); o1[7] = f2bf(v3.w);
        int swz = (row & 7) << 4;
        char* base = (char*)Bl + row * 128;
        *(u16x8*)(base + ((q * 32)      ^ swz)) = o0;
        *(u16x8*)(base + ((q * 32 + 16) ^ swz)) = o1;
      }
    }
    __syncthreads();
#pragma unroll
    for (int kk = 0; kk < 2; ++kk) {
      s16x8 af[4], bfr[4];
#pragma unroll
      for (int i = 0; i < 4; ++i) {
        int ra = wm * 64 + i * 16 + lo;
        int ca = (kk * 4 + hi) * 16; if (AM != 1) ca ^= (ra & 7) << 4;
        af[i]  = *(const s16x8*)((const char*)Al + ra * 128 + ca);
        int rb = wn * 64 + i * 16 + lo;
        int cb = (kk * 4 + hi) * 16; if (WM != 1) cb ^= (rb & 7) << 4;
        bfr[i] = *(const s16x8*)((const char*)Bl + rb * 128 + cb);
      }
#pragma unroll
      for (int i = 0; i < 4; ++i)
#pragma unroll
        for (int j = 0; j < 4; ++j)
          acc[i][j] = __builtin_amdgcn_mfma_f32_16x16x32_bf16(af[i], bfr[j], acc[i][j], 0, 0, 0);
    }
  }

  const int mb = m0 + wm * 64, nb = n0 + wn * 64;
  if (EPI == 0) {
    u16* Out = (u16*)Cp;
#pragma unroll
    for (int i = 0; i < 4; ++i)
#pragma unroll
      for (int j = 0; j < 4; ++j) {
        int n = nb + j * 16 + lo;
        int h = n >> 7, d = n & 127;
#pragma unroll
        for (int r = 0; r < 4; ++r) {
          int m = mb + i * 16 + hi * 4 + r;
          int b = m >> 11, s = m & 2047;
          Out[((size_t)((b * 16 + h) * 2048 + s)) * 128 + d] = f2bf(acc[i][j][r]);
        }
      }
  } else if (EPI == 1) {
    u16* Out = (u16*)Cp;
#pragma unroll
    for (int i = 0; i < 4; ++i)
#pragma unroll
      for (int j = 0; j < 4; ++j) {
        int n = nb + j * 16 + lo;
        int h = n >> 7, d = n & 127;
        int m = mb + i * 16 + hi * 4;
        int b = m >> 11, s = m & 2047;
        u16x4 v;
#pragma unroll
        for (int r = 0; r < 4; ++r) v[r] = f2bf(acc[i][j][r]);
        *(u16x4*)(Out + ((size_t)((b * 16 + h) * 128 + d)) * 2048 + s) = v;
      }
  } else {
    float* Out = (float*)Cp;
#pragma unroll
    for (int i = 0; i < 4; ++i)
#pragma unroll
      for (int j = 0; j < 4; ++j) {
        int n = nb + j * 16 + lo;
#pragma unroll
        for (int r = 0; r < 4; ++r) {
          int m = mb + i * 16 + hi * 4 + r;
          Out[(size_t)m * 2048 + n] = acc[i][j][r];
        }
      }
  }
}

// ---------------------------------------------------------------------------
// RoPE in-place on K only (Q rope fused into attn Q staging)
// ---------------------------------------------------------------------------
__global__ __launch_bounds__(256)
void rope_k_kernel(u16* __restrict__ Kh, const int* __restrict__ pos)
{
  const int NP = 4 * 16 * 2048 * 64; // pairs
  const float C = -0.20762050593046014f; // -log2(10000)/64
  for (int idx = blockIdx.x * 256 + threadIdx.x; idx < NP; idx += gridDim.x * 256) {
    int i = idx & 63;
    int srow = idx >> 6;          // bh*2048 + s
    int s = srow & 2047;
    int b = srow >> 15;
    int p = pos[(b << 11) + s];
    float ang = (float)p * exp2f(C * (float)i);
    float sn, cs;
    sincosf(ang, &sn, &cs);
    u32* kp = (u32*)Kh + (size_t)srow * 64 + i;
    u32 v = *kp;
    float x1 = bf2f((u16)(v & 0xffffu)), x2 = bf2f((u16)(v >> 16));
    *kp = (u32)f2bf(x1 * cs - x2 * sn) | ((u32)f2bf(x1 * sn + x2 * cs) << 16);
  }
}

// ---------------------------------------------------------------------------
// Causal flash attention (R18 form): swapped-operand 32x32 +
// cooperative double-buffered K/V LDS staging + 16-deep XOR swizzles.
// ---------------------------------------------------------------------------
__global__ __launch_bounds__(256, 2)
void attn_kernel(const u16* __restrict__ Qh, const u16* __restrict__ Kh,
                 const u16* __restrict__ Vt, const int* __restrict__ pos,
                 u16* __restrict__ AO)
{
  __shared__ __attribute__((aligned(16))) char smem[65536];

  const int t = threadIdx.x, lane = t & 63, w = t >> 6;
  const int q5 = lane & 31, h5 = lane >> 5;
  const int bid = blockIdx.x;
  const int bh = (((bid >> 3) & 7) << 3) | (bid & 7);   // XCD-slot pinned
  const int qt = bid >> 6;                  // 0..15
  const int qbase = (15 - qt) * 128;        // heavy tiles dispatch first
  const int b = bh >> 4;
  const int qrow0 = qbase + w * 32;
  const int q_abs = qrow0 + q5;

  const u16* Kb = Kh + (size_t)bh * 2048 * 128;   // [2048][128]
  const u16* Vb = Vt + (size_t)bh * 128 * 2048;   // [128][2048]

  auto stageKV = [&](int kv0, char* dst) {
#pragma unroll
    for (int j = 0; j < 4; ++j) {           // K: 1024 16B-chunks, 16-deep swz
      int chunk = j * 256 + w * 64 + lane;
      int row = chunk >> 4, cc = chunk & 15;
      const u16* g = Kb + (size_t)(kv0 + row) * 128 + ((cc ^ (row & 15)) * 8);
      gload_lds16(g, dst + (size_t)chunk * 16);
    }
#pragma unroll
    for (int j = 0; j < 4; ++j) {           // V: folded 64x256B, 16-deep swz
      int chunk = j * 256 + w * 64 + lane;
      int pr = chunk >> 4, o16 = chunk & 15;
      int orig = o16 ^ (pr & 15);
      int grow = ((orig >> 3) << 6) + pr;   // logical row = half*64 + pr
      const u16* g = Vb + (size_t)grow * 2048 + kv0 + ((orig & 7) * 8);
      gload_lds16(g, dst + 16384 + (size_t)chunk * 16);
    }
  };

  // ---- Q fragments with fused RoPE; softmax scale folded (registers) ----
  s16x8 qb[8];
  const float CF = -0.20762050593046014f;   // -log2(10000)/64
  const float QSCALE = 0.08838834764831845f * 1.4426950408889634f;
  {
    float p = (float)pos[(b << 11) + q_abs];
    const u16* qrow = Qh + ((size_t)bh * 2048 + q_abs) * 128;
#pragma unroll
    for (int kb = 0; kb < 8; ++kb) {
      s16x8 raw = *reinterpret_cast<const s16x8*>(qrow + kb * 16 + h5 * 8);
      s16x8 out;
#pragma unroll
      for (int u = 0; u < 4; ++u) {
        float x1 = bf2f((u16)raw[2 * u]), x2 = bf2f((u16)raw[2 * u + 1]);
        float ang = p * exp2f(CF * (float)(kb * 8 + h5 * 4 + u));
        float sn, cs; sincosf(ang, &sn, &cs);
        sn *= QSCALE; cs *= QSCALE;
        out[2 * u]     = (short)f2bf(x1 * cs - x2 * sn);
        out[2 * u + 1] = (short)f2bf(x1 * sn + x2 * cs);
      }
      qb[kb] = out;
    }
  }

  f32x16 o[4];
#pragma unroll
  for (int d = 0; d < 4; ++d)
#pragma unroll
    for (int r = 0; r < 16; ++r) o[d][r] = 0.f;
  float m2 = -1e30f, lp = 0.f;

  const int ntiles = (qbase + 128) >> 6;

  stageKV(0, smem);
  if (ntiles > 1) stageKV(64, smem + 32768);

  for (int tile = 0; tile < ntiles; ++tile) {
    const int kv0 = tile << 6;
    if (tile < ntiles - 1) {
      asm volatile("s_waitcnt vmcnt(8)\n\ts_barrier" ::: "memory");
    } else {
      asm volatile("s_waitcnt vmcnt(0)\n\ts_barrier" ::: "memory");
    }
    const char* Kl = smem + (size_t)(tile & 1) * 32768;
    const char* Vl = Kl + 16384;

    // ---- S^T = K . Q : K fragments from LDS (16-deep swz) ----
    f32x16 st[2];
#pragma unroll
    for (int tt = 0; tt < 2; ++tt)
#pragma unroll
      for (int r = 0; r < 16; ++r) st[tt][r] = 0.f;
    __builtin_amdgcn_s_setprio(1);
#pragma unroll
    for (int tt = 0; tt < 2; ++tt) {
      const char* krow = Kl + (tt * 32 + q5) * 256;
      const int swz = (q5 & 15) << 4;     // (tt*32+q5)&15 == q5&15
#pragma unroll
      for (int kb = 0; kb < 8; ++kb) {
        s16x8 ka = *(const s16x8*)(krow + ((kb * 32 + h5 * 16) ^ swz));
        st[tt] = __builtin_amdgcn_mfma_f32_32x32x16_bf16(ka, qb[kb], st[tt], 0, 0, 0);
      }
    }
    __builtin_amdgcn_s_setprio(0);

    // ---- mask (diag tiles only) + per-lane max ----
    const bool needmask = (kv0 + 63 > qrow0);
    float pm = -1e30f;
    if (needmask) {
#pragma unroll
      for (int tt = 0; tt < 2; ++tt)
#pragma unroll
        for (int r = 0; r < 16; ++r) {
          int kvloc = (r & 3) + 8 * (r >> 2) + 4 * h5 + 32 * tt;
          float v = st[tt][r];
          if (kv0 + kvloc > q_abs) v = -1e30f;
          st[tt][r] = v;
          pm = fmaxf(pm, v);
        }
    } else {
#pragma unroll
      for (int tt = 0; tt < 2; ++tt)
#pragma unroll
        for (int r = 0; r < 16; ++r) pm = fmaxf(pm, st[tt][r]);
    }

    // ---- deferred-max: vote only; rescale = scalar alpha per lane ----
    if (__any(pm - m2 > 8.0f)) {
      float tm = fmaxf(pm, __shfl_xor(pm, 32));
      float mn = fmaxf(m2, tm);
      float alpha = exp2f(m2 - mn);
      m2 = mn; lp *= alpha;
#pragma unroll
      for (int d = 0; d < 4; ++d)
#pragma unroll
        for (int r = 0; r < 16; ++r) o[d][r] *= alpha;
    }

    // ---- exp2 + pack + partner exchange, per-tt (short live ranges) ----
    s16x8 pb[2][2];
#pragma unroll
    for (int tt = 0; tt < 2; ++tt) {
      u32 pk[8], sw[8];
      float acc = 0.f;
#pragma unroll
      for (int i = 0; i < 8; ++i) {
        float e0 = exp2f(st[tt][2 * i]     - m2);
        float e1 = exp2f(st[tt][2 * i + 1] - m2);
        acc += e0 + e1;
        pk[i] = (u32)f2bf(e0) | ((u32)f2bf(e1) << 16);
      }
      lp += acc;
#pragma unroll
      for (int i = 0; i < 8; ++i)
        sw[i] = (u32)__shfl_xor((int)pk[i], 32);
#pragma unroll
      for (int kv2 = 0; kv2 < 2; ++kv2) {
        int i0 = kv2 * 4;
        u32x4 tmp;
        tmp[0] = h5 ? sw[i0 + 2] : pk[i0];
        tmp[1] = h5 ? sw[i0 + 3] : pk[i0 + 1];
        tmp[2] = h5 ? pk[i0 + 2] : sw[i0];
        tmp[3] = h5 ? pk[i0 + 3] : sw[i0 + 1];
        pb[tt][kv2] = __builtin_bit_cast(s16x8, tmp);
      }
    }

    // ---- O^T += V^T . P^T : V from folded LDS tile (16-deep swz) ----
    __builtin_amdgcn_s_setprio(1);
#pragma unroll
    for (int d = 0; d < 4; ++d) {
      const char* vrow = Vl + (((d & 1) * 32 + q5) * 256);
      const int vbase = (d >> 1) * 128;
      const int swz = (q5 & 15) << 4;     // pr&15 == q5&15
#pragma unroll
      for (int tt = 0; tt < 2; ++tt)
#pragma unroll
        for (int kv2 = 0; kv2 < 2; ++kv2) {
          s16x8 va = *(const s16x8*)(vrow + ((vbase + tt * 64 + kv2 * 32 + h5 * 16) ^ swz));
          o[d] = __builtin_amdgcn_mfma_f32_32x32x16_bf16(va, pb[tt][kv2], o[d], 0, 0, 0);
        }
    }
    __builtin_amdgcn_s_setprio(0);

    // ---- buffer free: drain LDS reads, then stage tile+2 into it ----
    asm volatile("s_waitcnt lgkmcnt(0)\n\ts_barrier" ::: "memory");
    if (tile + 2 < ntiles)
      stageKV((tile + 2) * 64, smem + (size_t)(tile & 1) * 32768);
  }

  // ---- finalize: one partner-sum shuffle, swizzled LDS repack, store ----
  float lt = lp + __shfl_xor(lp, 32);
  float inv = 1.0f / lt;
  __syncthreads();
  char* Olw = smem + w * 8192;   // 32 rows x 256 B per wave
#pragma unroll
  for (int d4 = 0; d4 < 4; ++d4)
#pragma unroll
    for (int r = 0; r < 16; ++r) {
      int dd = d4 * 32 + (r & 3) + 8 * (r >> 2) + 4 * h5;
      *(u16*)(Olw + q5 * 256 + ((dd * 2) ^ ((q5 & 7) << 4))) = f2bf(o[d4][r] * inv);
    }
  __syncthreads();
  const int h = bh & 15;
#pragma unroll
  for (int c = 0; c < 8; ++c) {
    int chunk = c * 256 + t;
    int row = chunk >> 4, sl = chunk & 15;
    u16x8 v = *(const u16x8*)(smem + row * 256 + ((sl * 16) ^ ((row & 7) << 4)));
    *(u16x8*)(AO + ((size_t)(b * 2048 + qbase + row)) * 2048 + h * 128 + sl * 8) = v;
  }
}

// ---------------------------------------------------------------------------
extern "C" void kernel_launch(void* const* d_in, const int* in_sizes, int n_in,
                              void* d_out, int out_size, void* d_ws, size_t ws_size,
                              hipStream_t stream)
{
  const float* x  = (const float*)d_in[0];
  const float* Wq = (const float*)d_in[1];
  const float* Wk = (const float*)d_in[2];
  const float* Wv = (const float*)d_in[3];
  const float* Wo = (const float*)d_in[4];
  const int*  pos = (const int*)d_in[5];

  char* ws = (char*)d_ws;
  const size_t MB32 = 33554432;
  u16* Qh = (u16*)(ws);
  u16* Kh = (u16*)(ws + MB32);
  u16* Vt = (u16*)(ws + 2 * MB32);

  dim3 blk(256);

  if (ws_size >= (size_t)167772160) {
    u16* xb = (u16*)(ws + 3 * MB32);   // 32 MiB; AO aliases this after x consumed
    u16* Wb = (u16*)(ws + 4 * MB32);   // Wq|Wk|Wv|Wo bf16, 8 MiB each
    u16* AO = xb;
    convert_kernel<<<2048, blk, 0, stream>>>(x, Wq, Wk, Wv, Wo, xb, Wb);
    gemm256<0, 24><<<768, 512, 0, stream>>>(xb, Wb, Qh, Kh, Vt, nullptr);
    rope_k_kernel<<<2048, blk, 0, stream>>>(Kh, pos);
    attn_kernel<<<1024, blk, 0, stream>>>(Qh, Kh, Vt, pos, AO);
    gemm256<1, 8><<<256, 512, 0, stream>>>(AO, Wb + 3 * 4194304, nullptr, nullptr, nullptr,
                                           (float*)d_out);
  } else {
    u16* AO = (u16*)(ws + 3 * MB32);
    dim3 gg(16, 64);
    gemm_nt<0, 0, 0><<<gg, blk, 0, stream>>>(x, Wq, Qh);
    gemm_nt<0, 0, 0><<<gg, blk, 0, stream>>>(x, Wk, Kh);
    gemm_nt<0, 0, 1><<<gg, blk, 0, stream>>>(x, Wv, Vt);
    rope_k_kernel<<<2048, blk, 0, stream>>>(Kh, pos);
    attn_kernel<<<1024, blk, 0, stream>>>(Qh, Kh, Vt, pos, AO);
    gemm_nt<1, 0, 2><<<gg, blk, 0, stream>>>(AO, Wo, d_out);
  }
}